// Round 1
// baseline (465.028 us; speedup 1.0000x reference)
//
#include <hip/hip_runtime.h>
#include <hip/hip_fp16.h>

// SageConv: z = [feat, (adj@ (feat@nW^T))/(rowsum(adj)+1)] @ lW^T
// N=8192, F=256, OUT=256. adj (268MB fp32) read once -> HBM-bound ~47us floor.
// Strategy: fp16 MFMA (no fp32 MFMA on CDNA4), deg fused into the adj stream.

typedef _Float16 v8h __attribute__((ext_vector_type(8)));
typedef _Float16 v4h __attribute__((ext_vector_type(4)));
typedef float    v4f __attribute__((ext_vector_type(4)));

#define MFMA16(a, b, c) __builtin_amdgcn_mfma_f32_16x16x32_f16((a), (b), (c), 0, 0, 0)

__device__ __forceinline__ v4h cvt4(v4f f) {
  v4h h;
  h[0] = (_Float16)f[0]; h[1] = (_Float16)f[1];
  h[2] = (_Float16)f[2]; h[3] = (_Float16)f[3];
  return h;
}

// ---------------- K0: fp32 -> fp16 conversions ----------------
// features: 524288 float4 | neigh_W: 16384 float4 | lin_W: 32768 float4
__global__ __launch_bounds__(256) void k0_convert(
    const float* __restrict__ feat, const float* __restrict__ nW,
    const float* __restrict__ lW, _Float16* __restrict__ feat_h,
    _Float16* __restrict__ nW_h, _Float16* __restrict__ lW_h) {
  int i = blockIdx.x * 256 + threadIdx.x;
  if (i < 524288) {
    v4f f = reinterpret_cast<const v4f*>(feat)[i];
    reinterpret_cast<v4h*>(feat_h)[i] = cvt4(f);
  } else if (i < 524288 + 16384) {
    int j = i - 524288;
    v4f f = reinterpret_cast<const v4f*>(nW)[j];
    reinterpret_cast<v4h*>(nW_h)[j] = cvt4(f);
  } else if (i < 524288 + 16384 + 32768) {
    int j = i - (524288 + 16384);
    v4f f = reinterpret_cast<const v4f*>(lW)[j];
    reinterpret_cast<v4h*>(lW_h)[j] = cvt4(f);
  }
}

// ---------------- K1: hT[n][k] = sum_f nW[n][f] * feat[k][f] ----------------
// Stored K-major [256][8192] fp16 so K2 B-fragments are contiguous.
// A = nW_h [M=n=256, K=f], B[f][k] = feat_h[k][f]. grid 128 x 256thr.
__global__ __launch_bounds__(256) void k1_neigh(
    const _Float16* __restrict__ feat_h, const _Float16* __restrict__ nW_h,
    _Float16* __restrict__ hT) {
  int bid = blockIdx.x;
  int nb = bid & 3;         // n-tile (64 wide)
  int kt = bid >> 2;        // k-tile (256 wide)
  int l = threadIdx.x & 63, w = threadIdx.x >> 6;
  int lr = l & 15, kb = l >> 4;
  int n0 = nb * 64 + w * 16;
  int k0b = kt * 256;
  v4f acc[16] = {};
  for (int fi = 0; fi < 8; ++fi) {
    int f0 = fi * 32 + kb * 8;
    v8h a = *reinterpret_cast<const v8h*>(&nW_h[(n0 + lr) * 256 + f0]);
#pragma unroll
    for (int j = 0; j < 16; ++j) {
      v8h b = *reinterpret_cast<const v8h*>(&feat_h[(k0b + 16 * j + lr) * 256 + f0]);
      acc[j] = MFMA16(a, b, acc[j]);
    }
  }
#pragma unroll
  for (int j = 0; j < 16; ++j)
#pragma unroll
    for (int r = 0; r < 4; ++r)
      hT[(size_t)(n0 + 4 * kb + r) * 8192 + k0b + 16 * j + lr] = (_Float16)acc[j][r];
}

// ---------------- K2: part[ks][m][n] = adj[m, kchunk] @ h[kchunk, n] --------
// BM=64, BN=256(full), Ksplit=2 (4096 each). grid 256 x 512thr (8 waves).
// deg partial rowsums fused into the fp32 staging loads.
__global__ __launch_bounds__(512) void k2_agg(
    const float* __restrict__ adj, const _Float16* __restrict__ hT,
    float* __restrict__ part, float* __restrict__ degpart) {
  __shared__ _Float16 a_lds[64 * 40];  // stride 40 halves (80B) -> even bank spread
  int bid = blockIdx.x;
  int mt = bid >> 1, kh = bid & 1;
  int ms = mt * 64, ks = kh * 4096;
  int t = threadIdx.x;
  int l = t & 63, w = t >> 6;
  int lr = l & 15, kb = l >> 4;
  int srow = t >> 3, scol = (t & 7) * 4;  // staging: 64 rows x 32 k per iter

  const float* aptr = adj + (size_t)(ms + srow) * 8192 + ks + scol;
  const _Float16* bbase = hT + (size_t)(w * 32 + lr) * 8192 + ks + kb * 8;
  const _Float16* albase = a_lds + lr * 40 + kb * 8;

  float dsum = 0.f;
  v4f acc[4][2] = {};

  v4f fcur = __builtin_nontemporal_load(reinterpret_cast<const v4f*>(aptr));
  for (int kk = 0; kk < 128; ++kk) {
    dsum += fcur[0] + fcur[1] + fcur[2] + fcur[3];
    *reinterpret_cast<v4h*>(&a_lds[srow * 40 + scol]) = cvt4(fcur);
    __syncthreads();
    int nk = (kk < 127) ? kk + 1 : 127;  // prefetch next adj tile across MFMA phase
    v4f fnext = __builtin_nontemporal_load(reinterpret_cast<const v4f*>(aptr + nk * 32));
    v8h afr[4];
#pragma unroll
    for (int mf = 0; mf < 4; ++mf)
      afr[mf] = *reinterpret_cast<const v8h*>(albase + mf * 16 * 40);
#pragma unroll
    for (int nf = 0; nf < 2; ++nf) {
      v8h b = *reinterpret_cast<const v8h*>(bbase + (size_t)nf * 16 * 8192 + kk * 32);
#pragma unroll
      for (int mf = 0; mf < 4; ++mf)
        acc[mf][nf] = MFMA16(afr[mf], b, acc[mf][nf]);
    }
    __syncthreads();
    fcur = fnext;
  }
  // reduce deg over the 8 threads sharing a staging row (same wave)
  dsum += __shfl_xor(dsum, 1);
  dsum += __shfl_xor(dsum, 2);
  dsum += __shfl_xor(dsum, 4);
  if ((t & 7) == 0) degpart[kh * 8192 + ms + srow] = dsum;
  // store fp32 partials
#pragma unroll
  for (int mf = 0; mf < 4; ++mf)
#pragma unroll
    for (int nf = 0; nf < 2; ++nf)
#pragma unroll
      for (int r = 0; r < 4; ++r)
        part[(size_t)kh * 2097152 +
             (size_t)(ms + 16 * mf + 4 * kb + r) * 256 + w * 32 + 16 * nf + lr] =
            acc[mf][nf][r];
}

// ---------------- K3: z = [feat | (p0+p1)/(deg+1)] @ lW^T ----------------
// M=8192, N=256, K=512. Tile 128x64, grid 256 x 256thr.
__global__ __launch_bounds__(256) void k3_out(
    const _Float16* __restrict__ feat_h, const _Float16* __restrict__ lW_h,
    const float* __restrict__ part, const float* __restrict__ degpart,
    float* __restrict__ out) {
  int bid = blockIdx.x;
  int mt = bid >> 2, nt = bid & 3;
  int ms = mt * 128, ns = nt * 64;
  int l = threadIdx.x & 63, w = threadIdx.x >> 6;
  int lr = l & 15, kb = l >> 4;
  int m0 = ms + w * 32;
  int rowv[2];
  float inv[2];
#pragma unroll
  for (int mf = 0; mf < 2; ++mf) {
    rowv[mf] = m0 + 16 * mf + lr;
    inv[mf] = 1.0f / (degpart[rowv[mf]] + degpart[8192 + rowv[mf]] + 1.0f);
  }
  v4f acc[2][4] = {};
  // K 0..255: self features
  for (int kk = 0; kk < 8; ++kk) {
    int k0 = kk * 32 + kb * 8;
    v8h a[2];
#pragma unroll
    for (int mf = 0; mf < 2; ++mf)
      a[mf] = *reinterpret_cast<const v8h*>(&feat_h[(size_t)rowv[mf] * 256 + k0]);
#pragma unroll
    for (int nf = 0; nf < 4; ++nf) {
      v8h b = *reinterpret_cast<const v8h*>(&lW_h[(size_t)(ns + 16 * nf + lr) * 512 + k0]);
#pragma unroll
      for (int mf = 0; mf < 2; ++mf) acc[mf][nf] = MFMA16(a[mf], b, acc[mf][nf]);
    }
  }
  // K 256..511: normalized aggregate, built in-register from partials
  for (int kk = 8; kk < 16; ++kk) {
    int k0 = kk * 32 + kb * 8;
    int c0 = k0 - 256;
    v8h a[2];
#pragma unroll
    for (int mf = 0; mf < 2; ++mf) {
      const float* p0 = part + (size_t)rowv[mf] * 256 + c0;
      const float* p1 = p0 + 2097152;
      v4f x0 = *reinterpret_cast<const v4f*>(p0);
      v4f x1 = *reinterpret_cast<const v4f*>(p0 + 4);
      v4f y0 = *reinterpret_cast<const v4f*>(p1);
      v4f y1 = *reinterpret_cast<const v4f*>(p1 + 4);
      v8h h;
#pragma unroll
      for (int j = 0; j < 4; ++j) {
        h[j] = (_Float16)((x0[j] + y0[j]) * inv[mf]);
        h[4 + j] = (_Float16)((x1[j] + y1[j]) * inv[mf]);
      }
      a[mf] = h;
    }
#pragma unroll
    for (int nf = 0; nf < 4; ++nf) {
      v8h b = *reinterpret_cast<const v8h*>(&lW_h[(size_t)(ns + 16 * nf + lr) * 512 + k0]);
#pragma unroll
      for (int mf = 0; mf < 2; ++mf) acc[mf][nf] = MFMA16(a[mf], b, acc[mf][nf]);
    }
  }
#pragma unroll
  for (int mf = 0; mf < 2; ++mf)
#pragma unroll
    for (int nf = 0; nf < 4; ++nf)
#pragma unroll
      for (int r = 0; r < 4; ++r)
        out[(size_t)(m0 + 16 * mf + 4 * kb + r) * 256 + ns + 16 * nf + lr] =
            acc[mf][nf][r];
}

extern "C" void kernel_launch(void* const* d_in, const int* in_sizes, int n_in,
                              void* d_out, int out_size, void* d_ws, size_t ws_size,
                              hipStream_t stream) {
  const float* feat = (const float*)d_in[0];   // [8192,256]
  const float* adj  = (const float*)d_in[1];   // [8192,8192]
  const float* nW   = (const float*)d_in[2];   // [256,256]
  const float* lW   = (const float*)d_in[3];   // [256,512]
  float* out = (float*)d_out;                  // [8192,256]

  char* ws = (char*)d_ws;
  // layout (bytes): part 16MB | degpart 64KB | hT 4MB | feat_h 4MB | nW_h 128KB | lW_h 256KB
  float*    part    = (float*)ws;
  float*    degpart = (float*)(ws + 16777216);
  _Float16* hT      = (_Float16*)(ws + 16777216 + 65536);
  _Float16* feat_h  = (_Float16*)(ws + 16777216 + 65536 + 4194304);
  _Float16* nW_h    = (_Float16*)(ws + 16777216 + 65536 + 8388608);
  _Float16* lW_h    = (_Float16*)(ws + 16777216 + 65536 + 8388608 + 131072);

  k0_convert<<<2240, 256, 0, stream>>>(feat, nW, lW, feat_h, nW_h, lW_h);
  k1_neigh<<<128, 256, 0, stream>>>(feat_h, nW_h, hT);
  k2_agg<<<256, 512, 0, stream>>>(adj, hT, part, degpart);
  k3_out<<<256, 256, 0, stream>>>(feat_h, lW_h, part, degpart, out);
}

// Round 3
// 436.916 us; speedup vs baseline: 1.0643x; 1.0643x over previous
//
#include <hip/hip_runtime.h>
#include <hip/hip_fp16.h>

// SageConv reshaped: z = feat@lWs^T + (adj @ g)/deg,  g = feat @ (nW^T @ lWn^T)
// N=8192, F=256. adj (268MB fp32) read once -> HBM floor ~47us.
// k2 = T3+T4 pipeline: global_load_lds staging of A(adj fp32) and B(gT fp16),
// 3-buffer rotation, counted vmcnt(12), consume phase is LDS+MFMA only.

typedef _Float16 v8h __attribute__((ext_vector_type(8)));
typedef _Float16 v4h __attribute__((ext_vector_type(4)));
typedef float    v4f __attribute__((ext_vector_type(4)));

#define MFMA16(a, b, c) __builtin_amdgcn_mfma_f32_16x16x32_f16((a), (b), (c), 0, 0, 0)

typedef __attribute__((address_space(1))) const unsigned GU;
typedef __attribute__((address_space(3))) unsigned LU;
#define GLDS16(gp, lp) \
  __builtin_amdgcn_global_load_lds((GU*)(const void*)(gp), (LU*)(void*)(lp), 16, 0, 0)

__device__ __forceinline__ v4h cvt4(v4f f) {
  v4h h;
  h[0] = (_Float16)f[0]; h[1] = (_Float16)f[1];
  h[2] = (_Float16)f[2]; h[3] = (_Float16)f[3];
  return h;
}

// ---------------- K0: conversions + nW transpose ----------------
__global__ __launch_bounds__(256) void k0_convert(
    const float* __restrict__ feat, const float* __restrict__ nW,
    const float* __restrict__ lW, _Float16* __restrict__ feat_h,
    _Float16* __restrict__ lWs_h, _Float16* __restrict__ lWn_h,
    _Float16* __restrict__ nWT_h) {
  int i = blockIdx.x * 256 + threadIdx.x;
  if (i < 524288) {                       // feat: 2M elems as v4
    v4f f = reinterpret_cast<const v4f*>(feat)[i];
    reinterpret_cast<v4h*>(feat_h)[i] = cvt4(f);
  } else if (i < 557056) {                // lW [256][512] -> lWs/lWn [256][256]
    int j = i - 524288;
    int o = j >> 7, c4 = j & 127;
    v4f f = reinterpret_cast<const v4f*>(lW)[j];
    if (c4 < 64) reinterpret_cast<v4h*>(lWs_h)[o * 64 + c4] = cvt4(f);
    else         reinterpret_cast<v4h*>(lWn_h)[o * 64 + (c4 - 64)] = cvt4(f);
  } else if (i < 573440) {                // nWT[f][c] = nW[c][f]
    int j = i - 557056;
    int f = j >> 6, c0 = (j & 63) * 4;
    v4h h;
#pragma unroll
    for (int u = 0; u < 4; ++u) h[u] = (_Float16)nW[(c0 + u) * 256 + f];
    reinterpret_cast<v4h*>(nWT_h)[(f * 256 + c0) >> 2] = h;
  }
}

// ---------------- K1a: W2T[o][f] = sum_c lWn[o][c] * nWT[f][c] ----------------
__global__ __launch_bounds__(256) void k1a_w2(
    const _Float16* __restrict__ lWn_h, const _Float16* __restrict__ nWT_h,
    _Float16* __restrict__ W2T_h) {
  int ot = blockIdx.x >> 2, ft = blockIdx.x & 3;
  int l = threadIdx.x & 63, w = threadIdx.x >> 6;
  int lr = l & 15, kb = l >> 4;
  int o0 = ot * 64 + w * 16, f0b = ft * 64;
  v4f acc[4] = {};
  for (int ci = 0; ci < 8; ++ci) {
    int c0 = ci * 32 + kb * 8;
    v8h a = *reinterpret_cast<const v8h*>(&lWn_h[(o0 + lr) * 256 + c0]);
#pragma unroll
    for (int j = 0; j < 4; ++j) {
      v8h b = *reinterpret_cast<const v8h*>(&nWT_h[(f0b + 16 * j + lr) * 256 + c0]);
      acc[j] = MFMA16(a, b, acc[j]);
    }
  }
#pragma unroll
  for (int j = 0; j < 4; ++j)
#pragma unroll
    for (int r = 0; r < 4; ++r)
      W2T_h[(o0 + 4 * kb + r) * 256 + f0b + 16 * j + lr] = (_Float16)acc[j][r];
}

// ---------------- K1b: gT[o][i] = sum_f W2T[o][f] * feat[i][f] ----------------
__global__ __launch_bounds__(256) void k1b_g(
    const _Float16* __restrict__ feat_h, const _Float16* __restrict__ W2T_h,
    _Float16* __restrict__ gT) {
  int kt = blockIdx.x >> 2, nb = blockIdx.x & 3;
  int l = threadIdx.x & 63, w = threadIdx.x >> 6;
  int lr = l & 15, kb = l >> 4;
  int o0 = nb * 64 + w * 16;
  int i0 = kt * 64;
  v4f acc[4] = {};
  for (int fi = 0; fi < 8; ++fi) {
    int f0 = fi * 32 + kb * 8;
    v8h a = *reinterpret_cast<const v8h*>(&W2T_h[(o0 + lr) * 256 + f0]);
#pragma unroll
    for (int j = 0; j < 4; ++j) {
      v8h b = *reinterpret_cast<const v8h*>(&feat_h[(size_t)(i0 + 16 * j + lr) * 256 + f0]);
      acc[j] = MFMA16(a, b, acc[j]);
    }
  }
#pragma unroll
  for (int j = 0; j < 4; ++j)
#pragma unroll
    for (int r = 0; r < 4; ++r)
      gT[(size_t)(o0 + 4 * kb + r) * 8192 + i0 + 16 * j + lr] = (_Float16)acc[j][r];
}

// ---------------- K2: part[ks] = adj[:, kslice] @ g[kslice, :], deg fused -----
#define LDS_BUF 24576   // A: 64x32 fp32 = 8KB at 0, B: 256x32 fp16 = 16KB at 8192

__device__ __forceinline__ void k2_consume(
    const char* abase, const char* bbase, int lr, int kb, int w,
    int qa0, int qa1, int qb, v4f (&acc)[4][4], float (&dsum)[4], int dodeg) {
  v8h bfr[4];
#pragma unroll
  for (int nf = 0; nf < 4; ++nf)
    bfr[nf] = *reinterpret_cast<const v8h*>(bbase + (w * 64 + nf * 16 + lr) * 64 + qb);
  v8h afr[4];
#pragma unroll
  for (int mf = 0; mf < 4; ++mf) {
    const char* rp = abase + (16 * mf + lr) * 128;
    v4f a0 = *reinterpret_cast<const v4f*>(rp + qa0);
    v4f a1 = *reinterpret_cast<const v4f*>(rp + qa1);
    if (dodeg)
      dsum[mf] += (a0[0] + a0[1] + a0[2] + a0[3]) + (a1[0] + a1[1] + a1[2] + a1[3]);
    v8h h;
#pragma unroll
    for (int u = 0; u < 4; ++u) { h[u] = (_Float16)a0[u]; h[4 + u] = (_Float16)a1[u]; }
    afr[mf] = h;
  }
#pragma unroll
  for (int nf = 0; nf < 4; ++nf)
#pragma unroll
    for (int mf = 0; mf < 4; ++mf)
      acc[mf][nf] = MFMA16(afr[mf], bfr[nf], acc[mf][nf]);
}

#define K2TAIL(T, WN)                                                        \
  asm volatile("s_waitcnt vmcnt(" #WN ")" ::: "memory");                     \
  __builtin_amdgcn_s_barrier();                                              \
  {                                                                          \
    const char* base2 = &smem[((T) % 3) * LDS_BUF];                          \
    k2_consume(base2, base2 + 8192, lr, kb, w, qa0, qa1, qb, acc, dsum, dodeg); \
  }

__global__ __launch_bounds__(256, 2) void k2_agg(
    const float* __restrict__ adj, const _Float16* __restrict__ gT,
    float* __restrict__ part, float* __restrict__ degpart) {
  __shared__ __align__(16) char smem[3 * LDS_BUF];
  int bid = blockIdx.x;
  // XCD-bijective: 8 XCDs, 2 per ksplit slice -> gT slice (1MB) L2-resident.
  int x = bid & 7, jj = bid >> 3;
  int ksi = x >> 1;
  int mt = ((x & 1) << 6) | jj;
  int ms = mt * 64;
  int ks = ksi * 2048;
  int tid = threadIdx.x;
  int l = tid & 63, w = tid >> 6;
  int lr = l & 15, kb = l >> 4;

  // A staging: chunks c=w*2+i (8 rows x 128B each); source pre-swizzled (rule 21)
  const float* aSrc[2];
#pragma unroll
  for (int i = 0; i < 2; ++i) {
    int rA = 16 * w + 8 * i + (l >> 3);
    unsigned cbA = ((unsigned)(l & 7) * 16) ^ (((unsigned)(rA & 7)) << 4);
    aSrc[i] = adj + (size_t)(ms + rA) * 8192 + ks + (cbA >> 2);
  }
  // B staging: chunks c=w*4+i (16 o-rows x 64B each)
  const _Float16* bSrc[4];
#pragma unroll
  for (int i = 0; i < 4; ++i) {
    int oB = 64 * w + 16 * i + (l >> 2);
    unsigned cbB = ((unsigned)(l & 3) * 16) ^ (((unsigned)(oB & 3)) << 4);
    bSrc[i] = gT + (size_t)oB * 8192 + ks + (cbB >> 1);
  }
  int qa0 = (kb * 32) ^ ((lr & 7) << 4);
  int qa1 = (kb * 32 + 16) ^ ((lr & 7) << 4);
  int qb = (kb * 16) ^ ((lr & 3) << 4);

  v4f acc[4][4] = {};
  float dsum[4] = {0.f, 0.f, 0.f, 0.f};
  int dodeg = (w == 0);

  auto stage = [&](int t) {
    char* base = &smem[(t % 3) * LDS_BUF];
#pragma unroll
    for (int i = 0; i < 2; ++i)
      GLDS16(aSrc[i] + t * 32, base + (w * 2 + i) * 1024);
#pragma unroll
    for (int i = 0; i < 4; ++i)
      GLDS16(bSrc[i] + t * 32, base + 8192 + (w * 4 + i) * 1024);
  };

  stage(0); stage(1); stage(2);          // 18 loads/wave in flight
  for (int t = 0; t < 62; ++t) {
    asm volatile("s_waitcnt vmcnt(12)" ::: "memory");  // tile t done; t+1,t+2 in flight
    __builtin_amdgcn_s_barrier();
    {
      const char* base = &smem[(t % 3) * LDS_BUF];
      k2_consume(base, base + 8192, lr, kb, w, qa0, qa1, qb, acc, dsum, dodeg);
    }
    // ensure this wave's ds_reads of buf[t%3] are retired before any wave
    // restages into the same buffer (closes a theoretical ds vs glds race)
    asm volatile("s_waitcnt lgkmcnt(0)" ::: "memory");
    __builtin_amdgcn_s_barrier();        // all waves done reading buf before restage
    if (t < 61) stage(t + 3);
  }
  K2TAIL(62, 6)
  K2TAIL(63, 0)

  if (dodeg) {
#pragma unroll
    for (int mf = 0; mf < 4; ++mf) {
      float d = dsum[mf];
      d += __shfl_xor(d, 16);
      d += __shfl_xor(d, 32);
      if (kb == 0) degpart[ksi * 8192 + ms + 16 * mf + lr] = d;
    }
  }
  float* pbase = part + (size_t)ksi * 2097152 + (size_t)ms * 256 + w * 64;
#pragma unroll
  for (int mf = 0; mf < 4; ++mf)
#pragma unroll
    for (int nf = 0; nf < 4; ++nf)
#pragma unroll
      for (int r = 0; r < 4; ++r)
        pbase[(size_t)(16 * mf + 4 * kb + r) * 256 + 16 * nf + lr] = acc[mf][nf][r];
}

// ---------------- K3: z = feat@lWs^T + (sum part)/(1+deg) ----------------
__global__ __launch_bounds__(256) void k3_out(
    const _Float16* __restrict__ feat_h, const _Float16* __restrict__ lWs_h,
    const float* __restrict__ part, const float* __restrict__ degpart,
    float* __restrict__ out) {
  int mt = blockIdx.x >> 2, nt = blockIdx.x & 3;
  int ms = mt * 64, ns = nt * 64;
  int l = threadIdx.x & 63, w = threadIdx.x >> 6;
  int lr = l & 15, kb = l >> 4;
  int m0 = ms + w * 16;
  v4f acc[4] = {};
  for (int fi = 0; fi < 8; ++fi) {
    int f0 = fi * 32 + kb * 8;
    v8h a = *reinterpret_cast<const v8h*>(&feat_h[(size_t)(m0 + lr) * 256 + f0]);
#pragma unroll
    for (int nf = 0; nf < 4; ++nf) {
      v8h b = *reinterpret_cast<const v8h*>(&lWs_h[(ns + 16 * nf + lr) * 256 + f0]);
      acc[nf] = MFMA16(a, b, acc[nf]);
    }
  }
  float inv[4];
#pragma unroll
  for (int r = 0; r < 4; ++r) {
    int m = m0 + 4 * kb + r;
    float d = 1.0f;
#pragma unroll
    for (int s = 0; s < 4; ++s) d += degpart[s * 8192 + m];
    inv[r] = 1.0f / d;
  }
#pragma unroll
  for (int nf = 0; nf < 4; ++nf)
#pragma unroll
    for (int r = 0; r < 4; ++r) {
      int m = m0 + 4 * kb + r;
      int o = ns + 16 * nf + lr;
      float p = 0.f;
#pragma unroll
      for (int s = 0; s < 4; ++s)
        p += part[(size_t)s * 2097152 + (size_t)m * 256 + o];
      out[(size_t)m * 256 + o] = acc[nf][r] + p * inv[r];
    }
}

extern "C" void kernel_launch(void* const* d_in, const int* in_sizes, int n_in,
                              void* d_out, int out_size, void* d_ws, size_t ws_size,
                              hipStream_t stream) {
  const float* feat = (const float*)d_in[0];   // [8192,256]
  const float* adj  = (const float*)d_in[1];   // [8192,8192]
  const float* nW   = (const float*)d_in[2];   // [256,256]
  const float* lW   = (const float*)d_in[3];   // [256,512]
  float* out = (float*)d_out;                  // [8192,256]

  char* ws = (char*)d_ws;
  float*    part    = (float*)ws;                          // 32 MB
  float*    degpart = (float*)(ws + 33554432);             // 128 KB
  _Float16* gT      = (_Float16*)(ws + 33685504);          // 4 MB
  _Float16* feat_h  = (_Float16*)(ws + 37879808);          // 4 MB
  _Float16* lWs_h   = (_Float16*)(ws + 42074112);          // 128 KB
  _Float16* lWn_h   = (_Float16*)(ws + 42205184);          // 128 KB
  _Float16* nWT_h   = (_Float16*)(ws + 42336256);          // 128 KB
  _Float16* W2T_h   = (_Float16*)(ws + 42467328);          // 128 KB

  k0_convert<<<2240, 256, 0, stream>>>(feat, nW, lW, feat_h, lWs_h, lWn_h, nWT_h);
  k1a_w2<<<16, 256, 0, stream>>>(lWn_h, nWT_h, W2T_h);
  k1b_g<<<512, 256, 0, stream>>>(feat_h, W2T_h, gT);
  k2_agg<<<512, 256, 0, stream>>>(adj, gT, part, degpart);
  k3_out<<<512, 256, 0, stream>>>(feat_h, lWs_h, part, degpart, out);
}